// Round 17
// baseline (461.953 us; speedup 1.0000x reference)
//
#include <hip/hip_runtime.h>
#include <hip/hip_bf16.h>
#include <math.h>

// Problem constants
#define Bsz 8
#define Lseq 2048
#define ENC_IN 21
#define C_OUT 21
#define D_MODEL 512
#define D_INNER 1024
#define D_STATE 16
#define D_CONV 4
#define DT_RANK 32
#define MARK_DIM 4
#define PRED_LEN 96
#define L_TAIL (Lseq - PRED_LEN)   // 1952
#define K_EMB 80                   // 63 conv taps + 4 mark + 13 zero-pad
#define CHUNK 128
#define NCHUNK_A 15                // chunks 0..14 in pass A; chunk 15 in pass B
#define MTOT (Bsz * Lseq)          // 16384
#define PITCH (MTOT + 16)          // 16400 floats (65600 B rows)

#define PE_C0 (-9.210340371976184f / (float)D_MODEL)   // -ln(10000)/d_model

typedef __attribute__((ext_vector_type(8))) short short8;
typedef __attribute__((ext_vector_type(4))) float f32x4;

// ---------------------------------------------------------------------------
// 1) Instance-norm stats: one-pass mean/std per (b, c)
// ---------------------------------------------------------------------------
__global__ void stats_kernel(const float* __restrict__ x_enc,
                             float* __restrict__ mean, float* __restrict__ stdv) {
    int bc = blockIdx.x;               // 0..167
    int b = bc / ENC_IN, c = bc % ENC_IN;
    __shared__ float red[256], red2[256];
    int t = threadIdx.x;
    float s = 0.f, s2 = 0.f;
    for (int l = t; l < Lseq; l += 256) {
        float x = x_enc[((size_t)b * Lseq + l) * ENC_IN + c];
        s += x; s2 += x * x;
    }
    red[t] = s; red2[t] = s2; __syncthreads();
    for (int off = 128; off > 0; off >>= 1) {
        if (t < off) { red[t] += red[t + off]; red2[t] += red2[t + off]; }
        __syncthreads();
    }
    if (t == 0) {
        float m = red[0] / (float)Lseq;
        float v = red2[0] / (float)Lseq - m * m;
        mean[bc] = m;
        stdv[bc] = sqrtf(fmaxf(v, 0.f) + 1e-5f);
    }
}

// ---------------------------------------------------------------------------
// 2) Fuse head_w @ out_proj_w -> W (21 x 1024)
// ---------------------------------------------------------------------------
__global__ void fuse_w_kernel(const float* __restrict__ head_w,
                              const float* __restrict__ out_proj_w,
                              float* __restrict__ W) {
    int idx = blockIdx.x * 256 + threadIdx.x;
    if (idx >= C_OUT * D_INNER) return;
    int c = idx / D_INNER, d = idx % D_INNER;
    float s = 0.f;
    for (int k = 0; k < D_MODEL; ++k)
        s += head_w[c * D_MODEL + k] * out_proj_w[(size_t)k * D_INNER + d];
    W[idx] = s;
}

// ---------------------------------------------------------------------------
// 3a) Pack embedding weights TRANSPOSED: WembT[k][d]
// ---------------------------------------------------------------------------
__global__ void prep_wT_kernel(const float* __restrict__ conv_w,
                               const float* __restrict__ temp_w,
                               float* __restrict__ WembT) {
    int idx = blockIdx.x * 256 + threadIdx.x;        // 80*512 exact
    int k = idx / D_MODEL, d = idx % D_MODEL;
    float v = 0.f;
    if (k < 3 * ENC_IN) {
        int kk = k / ENC_IN, c = k % ENC_IN;
        v = conv_w[((size_t)d * ENC_IN + c) * 3 + kk];
    } else if (k < 3 * ENC_IN + MARK_DIM) {
        v = temp_w[d * MARK_DIM + (k - 3 * ENC_IN)];
    }
    WembT[idx] = v;
}

// ---------------------------------------------------------------------------
// 3b) Build xin[bl][k] ROW-MAJOR
// ---------------------------------------------------------------------------
__global__ void prep_x_kernel(const float* __restrict__ x_enc,
                              const float* __restrict__ x_mark,
                              const float* __restrict__ mean,
                              const float* __restrict__ stdv,
                              float* __restrict__ xin) {
    int idx = blockIdx.x * 256 + threadIdx.x;        // 16384*80 exact
    int bl = idx / K_EMB, k = idx % K_EMB;
    int b = bl >> 11, l = bl & (Lseq - 1);
    float v = 0.f;
    if (k < 3 * ENC_IN) {
        int kk = k / ENC_IN, c = k % ENC_IN;
        int ll = (l + kk - 1 + Lseq) & (Lseq - 1);
        v = (x_enc[((size_t)b * Lseq + ll) * ENC_IN + c] - mean[b * ENC_IN + c])
            / stdv[b * ENC_IN + c];
    } else if (k < 3 * ENC_IN + MARK_DIM) {
        v = x_mark[((size_t)b * Lseq + l) * MARK_DIM + (k - 3 * ENC_IN)];
    }
    xin[idx] = v;
}

// ---------------------------------------------------------------------------
// 3c) Wcomb[j][k] = sum_d in_proj_w[j][d] * WembT[k][d]   (2048 x 80)
// ---------------------------------------------------------------------------
__global__ void wcomb_kernel(const float* __restrict__ in_proj_w,
                             const float* __restrict__ WembT,
                             float* __restrict__ Wcomb) {
    int idx = blockIdx.x * 256 + threadIdx.x;        // 2048*80 exact
    int j = idx / K_EMB, k = idx % K_EMB;
    const float* a = in_proj_w + (size_t)j * D_MODEL;
    const float* b = WembT + (size_t)k * D_MODEL;
    float s = 0.f;
    for (int d = 0; d < D_MODEL; d += 4) {
        float4 av = *(const float4*)(a + d);
        float4 bv = *(const float4*)(b + d);
        s += av.x * bv.x + av.y * bv.y + av.z * bv.z + av.w * bv.w;
    }
    Wcomb[idx] = s;
}

// ---------------------------------------------------------------------------
// 3d) PEpZ[lz][j] = pe[1952+lz][:] . in_proj_w[1024+j][:]  (96 x 1024)
// ---------------------------------------------------------------------------
__global__ void pepz_kernel(const float* __restrict__ in_proj_w,
                            float* __restrict__ PEpZ) {
    __shared__ float per[D_MODEL];
    int lz = blockIdx.x;                  // 0..95
    int q = blockIdx.y;                   // 0..3
    int t = threadIdx.x;
    {
        int l = L_TAIL + lz;
        float div = __expf((float)(2 * t) * PE_C0);
        float s, c;
        sincosf((float)l * div, &s, &c);
        per[2 * t] = s;
        per[2 * t + 1] = c;
    }
    __syncthreads();
    int j = q * 256 + t;
    const float* w = in_proj_w + (size_t)(D_INNER + j) * D_MODEL;
    float s = 0.f;
    for (int d = 0; d < D_MODEL; d += 4) {
        float4 wv = *(const float4*)(w + d);
        s += per[d] * wv.x + per[d + 1] * wv.y + per[d + 2] * wv.z + per[d + 3] * wv.w;
    }
    PEpZ[(size_t)lz * D_INNER + j] = s;
}

// ---------------------------------------------------------------------------
// 4a) Small fp32 GEMM (z96 tail slice).
// ---------------------------------------------------------------------------
template <int AMODE, int BMODE, int EPI>
__launch_bounds__(256)
__global__ void gemm(const float* __restrict__ A, const float* __restrict__ B,
                     float* __restrict__ C0, const float* __restrict__ bias,
                     int M, int N, int K, int lda, int ldb) {
    __shared__ float As[16][65];
    __shared__ float Bs[16][65];
    int bm = blockIdx.y, bn = blockIdx.x;
    int t = threadIdx.x;
    int tx = t & 15, ty = t >> 4;
    float acc[4][4] = {};
    int arow = bm * 64, bcol = bn * 64;
    int lr = t >> 2;
    int lk = (t & 3) * 4;

    size_t aRow;
    {
        int r = arow + lr;
        if (AMODE == 3) {
            int rb = r / PRED_LEN;
            int rl = r - rb * PRED_LEN;
            aRow = (size_t)rb * Lseq + L_TAIL + rl;
        } else {
            aRow = (size_t)r;
        }
    }

    for (int k0 = 0; k0 < K; k0 += 16) {
        {
            float4 av = *(const float4*)(A + aRow * lda + k0 + lk);
            As[lk + 0][lr] = av.x; As[lk + 1][lr] = av.y;
            As[lk + 2][lr] = av.z; As[lk + 3][lr] = av.w;
        }
        {
            float4 bv = *(const float4*)(B + (size_t)(bcol + lr) * ldb + k0 + lk);
            Bs[lk + 0][lr] = bv.x; Bs[lk + 1][lr] = bv.y;
            Bs[lk + 2][lr] = bv.z; Bs[lk + 3][lr] = bv.w;
        }
        __syncthreads();
        #pragma unroll
        for (int kk = 0; kk < 16; ++kk) {
            float a[4], bq[4];
            #pragma unroll
            for (int i = 0; i < 4; ++i) a[i] = As[kk][ty * 4 + i];
            #pragma unroll
            for (int j = 0; j < 4; ++j) bq[j] = Bs[kk][tx * 4 + j];
            #pragma unroll
            for (int i = 0; i < 4; ++i)
                #pragma unroll
                for (int j = 0; j < 4; ++j)
                    acc[i][j] += a[i] * bq[j];
        }
        __syncthreads();
    }

    #pragma unroll
    for (int i = 0; i < 4; ++i) {
        int row = arow + ty * 4 + i;
        #pragma unroll
        for (int j = 0; j < 4; ++j) {
            int col = bcol + tx * 4 + j;
            float v = acc[i][j];
            if (EPI == 3) {
                v += bias[(size_t)(row % PRED_LEN) * N + col];
            }
            C0[(size_t)row * N + col] = v;
        }
    }
}

// ---------------------------------------------------------------------------
// helper: fp32 -> (hi, lo) bf16 bit patterns (truncation split)
// ---------------------------------------------------------------------------
__device__ __forceinline__ void split_bf16(float x, short& hb, short& lb) {
    unsigned u = __float_as_uint(x);
    unsigned short h = (unsigned short)(u >> 16);
    float hf = __uint_as_float(((unsigned)h) << 16);
    unsigned short l = (unsigned short)(__float_as_uint(x - hf) >> 16);
    hb = (short)h; lb = (short)l;
}

// ---------------------------------------------------------------------------
// 4b) Split-bf16 MFMA GEMM, 128(M) x 64(N) tile, K-step 32, 4 waves.
//     BMODE 0: B k-major  BMODE 1: analytic PE  BMODE 2: B row-major [n][k]
//     EPI 0: none   1: +bias[row], softplus   2: +bias[row*2048+(col&2047)]
//     EPI 3: +bias (PE), then FUSED causal depthwise conv1d(k=4) + SiLU.
//            Boundary cols (bn0-1..3) recomputed in fp32; batch boundaries
//            align with 64-wide tiles so zeroed boundary = causal mask.
//            LDS staging buffers are byte-aliased with the epilogue tile.
// ---------------------------------------------------------------------------
template <int BMODE, int EPI>
__launch_bounds__(256)
__global__ void mfma_gemm128(const float* __restrict__ A, const float* __restrict__ B,
                             float* __restrict__ C, const float* __restrict__ bias,
                             const float* __restrict__ cw, const float* __restrict__ cb,
                             int M, int N, int K, int lda, int ldb, int ldc) {
    __shared__ __align__(16) char smem[36864];
    short (*Ah)[48] = (short(*)[48])(smem);            // 128x48x2 = 12288
    short (*Al)[48] = (short(*)[48])(smem + 12288);    // 12288
    short (*Bh)[48] = (short(*)[48])(smem + 24576);    // 64x48x2 = 6144
    short (*Bl)[48] = (short(*)[48])(smem + 30720);    // 6144
    float (*tile)[68] = (float(*)[68])(smem);          // 128x68x4 = 34816 (EPI 3)

    int t = threadIdx.x;
    int bn0 = blockIdx.x * 64;
    int am0 = blockIdx.y * 128;
    int w = t >> 6, l = t & 63;
    int lr = l & 15, lk = l >> 4;

    f32x4 acc[2][4];
    #pragma unroll
    for (int i = 0; i < 2; ++i)
        #pragma unroll
        for (int j = 0; j < 4; ++j) acc[i][j] = (f32x4){0.f, 0.f, 0.f, 0.f};

    const int mst = t >> 2, kst = (t & 3) * 8;

    for (int kb = 0; kb < K; kb += 32) {
        if (kb) __syncthreads();
        #pragma unroll
        for (int half = 0; half < 2; ++half) {
            int m = mst + half * 64;
            const float* src = A + (size_t)(am0 + m) * lda + kb + kst;
            short8 hv, lv;
            if (kb + 32 <= K) {
                float4 a0 = *(const float4*)(src);
                float4 a1 = *(const float4*)(src + 4);
                float xs[8] = {a0.x, a0.y, a0.z, a0.w, a1.x, a1.y, a1.z, a1.w};
                #pragma unroll
                for (int j = 0; j < 8; ++j) {
                    short hb, lb; split_bf16(xs[j], hb, lb);
                    hv[j] = hb; lv[j] = lb;
                }
            } else {
                #pragma unroll
                for (int j = 0; j < 8; ++j) {
                    float x = (kb + kst + j < K) ? src[j] : 0.f;
                    short hb, lb; split_bf16(x, hb, lb);
                    hv[j] = hb; lv[j] = lb;
                }
            }
            *(short8*)&Ah[m][kst] = hv;
            *(short8*)&Al[m][kst] = lv;
        }
        if constexpr (BMODE == 0) {
            short8 hv, lv;
            #pragma unroll
            for (int j = 0; j < 8; ++j) {
                int k = kb + kst + j;
                float x = (k < K) ? B[(size_t)k * ldb + bn0 + mst] : 0.f;
                short hb, lb; split_bf16(x, hb, lb);
                hv[j] = hb; lv[j] = lb;
            }
            *(short8*)&Bh[mst][kst] = hv;
            *(short8*)&Bl[mst][kst] = lv;
        } else if constexpr (BMODE == 1) {
            float ng = (float)(bn0 + mst);
            short8 hv, lv;
            #pragma unroll
            for (int p = 0; p < 4; ++p) {
                float e = __expf((float)(kb + kst + 2 * p) * PE_C0);
                float sv, cv;
                sincosf(ng * e, &sv, &cv);
                short hb, lb;
                split_bf16(sv, hb, lb); hv[2 * p] = hb; lv[2 * p] = lb;
                split_bf16(cv, hb, lb); hv[2 * p + 1] = hb; lv[2 * p + 1] = lb;
            }
            *(short8*)&Bh[mst][kst] = hv;
            *(short8*)&Bl[mst][kst] = lv;
        } else {
            const float* src = B + (size_t)(bn0 + mst) * ldb + kb + kst;
            short8 hv, lv;
            if (kb + 32 <= K) {
                float4 b0 = *(const float4*)(src);
                float4 b1 = *(const float4*)(src + 4);
                float xs[8] = {b0.x, b0.y, b0.z, b0.w, b1.x, b1.y, b1.z, b1.w};
                #pragma unroll
                for (int j = 0; j < 8; ++j) {
                    short hb, lb; split_bf16(xs[j], hb, lb);
                    hv[j] = hb; lv[j] = lb;
                }
            } else {
                #pragma unroll
                for (int j = 0; j < 8; ++j) {
                    float x = (kb + kst + j < K) ? src[j] : 0.f;
                    short hb, lb; split_bf16(x, hb, lb);
                    hv[j] = hb; lv[j] = lb;
                }
            }
            *(short8*)&Bh[mst][kst] = hv;
            *(short8*)&Bl[mst][kst] = lv;
        }
        __syncthreads();
        #pragma unroll
        for (int mt = 0; mt < 2; ++mt) {
            short8 a_hi = *(const short8*)&Ah[mt * 64 + w * 16 + lr][lk * 8];
            short8 a_lo = *(const short8*)&Al[mt * 64 + w * 16 + lr][lk * 8];
            #pragma unroll
            for (int t4 = 0; t4 < 4; ++t4) {
                short8 b_hi = *(const short8*)&Bh[t4 * 16 + lr][lk * 8];
                short8 b_lo = *(const short8*)&Bl[t4 * 16 + lr][lk * 8];
                acc[mt][t4] = __builtin_amdgcn_mfma_f32_16x16x32_bf16(a_hi, b_hi, acc[mt][t4], 0, 0, 0);
                acc[mt][t4] = __builtin_amdgcn_mfma_f32_16x16x32_bf16(a_lo, b_hi, acc[mt][t4], 0, 0, 0);
                acc[mt][t4] = __builtin_amdgcn_mfma_f32_16x16x32_bf16(a_hi, b_lo, acc[mt][t4], 0, 0, 0);
            }
        }
    }

    if constexpr (EPI == 3) {
        // fused conv epilogue: stage biased tile in LDS (aliases staging bufs)
        __syncthreads();
        #pragma unroll
        for (int mt = 0; mt < 2; ++mt) {
            #pragma unroll
            for (int t4 = 0; t4 < 4; ++t4) {
                #pragma unroll
                for (int r = 0; r < 4; ++r) {
                    int rl = mt * 64 + w * 16 + lk * 4 + r;
                    int cl = t4 * 16 + lr;
                    int col = bn0 + cl;
                    tile[rl][3 + cl] = acc[mt][t4][r]
                        + bias[(size_t)(am0 + rl) * Lseq + (col & (Lseq - 1))];
                }
            }
        }
        // boundary cols bn0-1..bn0-3 (zero when crossing a batch boundary)
        for (int idx = t; idx < 384; idx += 256) {
            int rl = idx / 3;
            int dlt = idx % 3 + 1;              // 1..3
            float val = 0.f;
            if ((bn0 & (Lseq - 1)) != 0) {
                int col = bn0 - dlt;
                const float* ar = A + (size_t)(am0 + rl) * lda;
                const float* br = B + (size_t)col * ldb;
                float s = 0.f;
                for (int k = 0; k < K; k += 4) {
                    float4 a4 = *(const float4*)(ar + k);
                    float4 b4 = *(const float4*)(br + k);
                    s += a4.x * b4.x + a4.y * b4.y + a4.z * b4.z + a4.w * b4.w;
                }
                val = s + bias[(size_t)(am0 + rl) * Lseq + (col & (Lseq - 1))];
            }
            tile[rl][3 - dlt] = val;
        }
        __syncthreads();
        // conv(k=4) + SiLU + store
        #pragma unroll
        for (int mt = 0; mt < 2; ++mt) {
            #pragma unroll
            for (int r = 0; r < 4; ++r) {
                int rl = mt * 64 + w * 16 + lk * 4 + r;
                int d = am0 + rl;
                float w0 = cw[d * D_CONV + 0], w1 = cw[d * D_CONV + 1];
                float w2 = cw[d * D_CONV + 2], w3 = cw[d * D_CONV + 3];
                float bs = cb[d];
                #pragma unroll
                for (int t4 = 0; t4 < 4; ++t4) {
                    int cl = t4 * 16 + lr;
                    float x0 = tile[rl][cl], x1 = tile[rl][cl + 1];
                    float x2 = tile[rl][cl + 2], x3 = tile[rl][cl + 3];
                    float o = bs + w0 * x0 + w1 * x1 + w2 * x2 + w3 * x3;
                    o = o / (1.f + __expf(-o));
                    C[(size_t)d * ldc + bn0 + cl] = o;
                }
            }
        }
    } else {
        #pragma unroll
        for (int mt = 0; mt < 2; ++mt) {
            #pragma unroll
            for (int t4 = 0; t4 < 4; ++t4) {
                #pragma unroll
                for (int r = 0; r < 4; ++r) {
                    int row = am0 + mt * 64 + w * 16 + lk * 4 + r;
                    int col = bn0 + t4 * 16 + lr;
                    float v = acc[mt][t4][r];
                    if (EPI == 1) {
                        v += bias[row];
                        v = (v > 20.f) ? v : log1pf(__expf(v));
                    }
                    if (EPI == 2) {
                        v += bias[(size_t)row * Lseq + (col & (Lseq - 1))];
                    }
                    C[(size_t)row * ldc + col] = v;
                }
            }
        }
    }
}

// ---------------------------------------------------------------------------
// 4b') Split-bf16 MFMA GEMM, 64(M) x 64(N) tile — PEpT. BMODE 1: analytic PE.
// ---------------------------------------------------------------------------
template <int BMODE, int EPI>
__launch_bounds__(256)
__global__ void mfma_gemm64(const float* __restrict__ A, const float* __restrict__ B,
                            float* __restrict__ C, const float* __restrict__ bias,
                            int M, int N, int K, int lda, int ldb, int ldc) {
    __shared__ short Ah[64][48], Al[64][48];
    __shared__ short Bh[64][48], Bl[64][48];
    int t = threadIdx.x;
    int bn0 = blockIdx.x * 64;
    int am0 = blockIdx.y * 64;
    int w = t >> 6, l = t & 63;
    int lr = l & 15, lk = l >> 4;

    f32x4 acc[4];
    #pragma unroll
    for (int i = 0; i < 4; ++i) acc[i] = (f32x4){0.f, 0.f, 0.f, 0.f};

    const int mst = t >> 2, kst = (t & 3) * 8;

    for (int kb = 0; kb < K; kb += 32) {
        if (kb) __syncthreads();
        {
            const float* src = A + (size_t)(am0 + mst) * lda + kb + kst;
            short8 hv, lv;
            if (kb + 32 <= K) {
                float4 a0 = *(const float4*)(src);
                float4 a1 = *(const float4*)(src + 4);
                float xs[8] = {a0.x, a0.y, a0.z, a0.w, a1.x, a1.y, a1.z, a1.w};
                #pragma unroll
                for (int j = 0; j < 8; ++j) {
                    short hb, lb; split_bf16(xs[j], hb, lb);
                    hv[j] = hb; lv[j] = lb;
                }
            } else {
                #pragma unroll
                for (int j = 0; j < 8; ++j) {
                    float x = (kb + kst + j < K) ? src[j] : 0.f;
                    short hb, lb; split_bf16(x, hb, lb);
                    hv[j] = hb; lv[j] = lb;
                }
            }
            *(short8*)&Ah[mst][kst] = hv;
            *(short8*)&Al[mst][kst] = lv;
        }
        if constexpr (BMODE == 1) {
            float ng = (float)(bn0 + mst);
            short8 hv, lv;
            #pragma unroll
            for (int p = 0; p < 4; ++p) {
                float e = __expf((float)(kb + kst + 2 * p) * PE_C0);
                float sv, cv;
                sincosf(ng * e, &sv, &cv);
                short hb, lb;
                split_bf16(sv, hb, lb); hv[2 * p] = hb; lv[2 * p] = lb;
                split_bf16(cv, hb, lb); hv[2 * p + 1] = hb; lv[2 * p + 1] = lb;
            }
            *(short8*)&Bh[mst][kst] = hv;
            *(short8*)&Bl[mst][kst] = lv;
        } else {
            short8 hv, lv;
            #pragma unroll
            for (int j = 0; j < 8; ++j) {
                int k = kb + kst + j;
                float x = (k < K) ? B[(size_t)k * ldb + bn0 + mst] : 0.f;
                short hb, lb; split_bf16(x, hb, lb);
                hv[j] = hb; lv[j] = lb;
            }
            *(short8*)&Bh[mst][kst] = hv;
            *(short8*)&Bl[mst][kst] = lv;
        }
        __syncthreads();
        short8 a_hi = *(const short8*)&Ah[w * 16 + lr][lk * 8];
        short8 a_lo = *(const short8*)&Al[w * 16 + lr][lk * 8];
        #pragma unroll
        for (int t4 = 0; t4 < 4; ++t4) {
            short8 b_hi = *(const short8*)&Bh[t4 * 16 + lr][lk * 8];
            short8 b_lo = *(const short8*)&Bl[t4 * 16 + lr][lk * 8];
            acc[t4] = __builtin_amdgcn_mfma_f32_16x16x32_bf16(a_hi, b_hi, acc[t4], 0, 0, 0);
            acc[t4] = __builtin_amdgcn_mfma_f32_16x16x32_bf16(a_lo, b_hi, acc[t4], 0, 0, 0);
            acc[t4] = __builtin_amdgcn_mfma_f32_16x16x32_bf16(a_hi, b_lo, acc[t4], 0, 0, 0);
        }
    }

    #pragma unroll
    for (int t4 = 0; t4 < 4; ++t4) {
        #pragma unroll
        for (int r = 0; r < 4; ++r) {
            int row = am0 + w * 16 + lk * 4 + r;
            int col = bn0 + t4 * 16 + lr;
            C[(size_t)row * ldc + col] = acc[t4][r];
        }
    }
}

// ---------------------------------------------------------------------------
// 4c) Split-K MFMA GEMM for x_proj (M=64), atomic accumulate (C pre-zeroed).
// ---------------------------------------------------------------------------
__launch_bounds__(256)
__global__ void mfma_gemm_splitk(const float* __restrict__ A, const float* __restrict__ B,
                                 float* __restrict__ C,
                                 int M, int N, int K, int lda, int ldb, int ldc,
                                 int ksplit) {
    __shared__ short Ah[64][48], Al[64][48];
    __shared__ short Bh[64][48], Bl[64][48];
    int t = threadIdx.x;
    int bn0 = blockIdx.x * 64;
    int kz0 = blockIdx.z * ksplit;
    int kz1 = min(K, kz0 + ksplit);
    int w = t >> 6, l = t & 63;
    int lr = l & 15, lk = l >> 4;

    f32x4 acc[4];
    #pragma unroll
    for (int i = 0; i < 4; ++i) acc[i] = (f32x4){0.f, 0.f, 0.f, 0.f};

    const int mst = t >> 2, kst = (t & 3) * 8;

    for (int kb = kz0; kb < kz1; kb += 32) {
        if (kb != kz0) __syncthreads();
        {
            const float* src = A + (size_t)mst * lda + kb + kst;
            float4 a0 = *(const float4*)(src);
            float4 a1 = *(const float4*)(src + 4);
            float xs[8] = {a0.x, a0.y, a0.z, a0.w, a1.x, a1.y, a1.z, a1.w};
            short8 hv, lv;
            #pragma unroll
            for (int j = 0; j < 8; ++j) {
                short hb, lb; split_bf16(xs[j], hb, lb);
                hv[j] = hb; lv[j] = lb;
            }
            *(short8*)&Ah[mst][kst] = hv;
            *(short8*)&Al[mst][kst] = lv;
        }
        {
            short8 hv, lv;
            #pragma unroll
            for (int j = 0; j < 8; ++j) {
                int k = kb + kst + j;
                float x = B[(size_t)k * ldb + bn0 + mst];
                short hb, lb; split_bf16(x, hb, lb);
                hv[j] = hb; lv[j] = lb;
            }
            *(short8*)&Bh[mst][kst] = hv;
            *(short8*)&Bl[mst][kst] = lv;
        }
        __syncthreads();
        short8 a_hi = *(const short8*)&Ah[w * 16 + lr][lk * 8];
        short8 a_lo = *(const short8*)&Al[w * 16 + lr][lk * 8];
        #pragma unroll
        for (int t4 = 0; t4 < 4; ++t4) {
            short8 b_hi = *(const short8*)&Bh[t4 * 16 + lr][lk * 8];
            short8 b_lo = *(const short8*)&Bl[t4 * 16 + lr][lk * 8];
            acc[t4] = __builtin_amdgcn_mfma_f32_16x16x32_bf16(a_hi, b_hi, acc[t4], 0, 0, 0);
            acc[t4] = __builtin_amdgcn_mfma_f32_16x16x32_bf16(a_lo, b_hi, acc[t4], 0, 0, 0);
            acc[t4] = __builtin_amdgcn_mfma_f32_16x16x32_bf16(a_hi, b_lo, acc[t4], 0, 0, 0);
        }
    }

    #pragma unroll
    for (int t4 = 0; t4 < 4; ++t4) {
        #pragma unroll
        for (int r = 0; r < 4; ++r) {
            int row = w * 16 + lk * 4 + r;
            int col = bn0 + t4 * 16 + lr;
            atomicAdd(&C[(size_t)row * ldc + col], acc[t4][r]);
        }
    }
}

// ---------------------------------------------------------------------------
// 4d) zero-init for the split-K output (xdblT, 64 x PITCH floats)
// ---------------------------------------------------------------------------
__global__ void zero_kernel(float4* __restrict__ p) {
    p[(size_t)blockIdx.x * 256 + threadIdx.x] = make_float4(0.f, 0.f, 0.f, 0.f);
}

// ---------------------------------------------------------------------------
// 4e) Transpose xdblT rank rows (32 x PITCH, k-major) -> xdbl_rm (MTOT x 32)
// ---------------------------------------------------------------------------
__global__ void xdbl_tr_kernel(const float* __restrict__ xdblT,
                               float* __restrict__ xdbl_rm) {
    __shared__ float tile[32][65];
    int l0 = blockIdx.x * 64;
    int t = threadIdx.x;
    {
        int p = t >> 3, ls = (t & 7) * 8;
        const float* src = xdblT + (size_t)p * PITCH + l0 + ls;
        float4 v0 = *(const float4*)(src);
        float4 v1 = *(const float4*)(src + 4);
        tile[p][ls + 0] = v0.x; tile[p][ls + 1] = v0.y;
        tile[p][ls + 2] = v0.z; tile[p][ls + 3] = v0.w;
        tile[p][ls + 4] = v1.x; tile[p][ls + 5] = v1.y;
        tile[p][ls + 6] = v1.z; tile[p][ls + 7] = v1.w;
    }
    __syncthreads();
    {
        int ll = t >> 2, ps = (t & 3) * 8;
        float o[8];
        #pragma unroll
        for (int j = 0; j < 8; ++j) o[j] = tile[ps + j][ll];
        float* dst = xdbl_rm + (size_t)(l0 + ll) * DT_RANK + ps;
        *(float4*)(dst)     = make_float4(o[0], o[1], o[2], o[3]);
        *(float4*)(dst + 4) = make_float4(o[4], o[5], o[6], o[7]);
    }
}

// ---------------------------------------------------------------------------
// 6a) Chunked scan, pass A — R13-proven 4-chain version (per-wave working
//     set ~16KB, under L1 capacity; 8-chain variants thrash, see R11/R15).
// ---------------------------------------------------------------------------
__launch_bounds__(256, 4)
__global__ void scanA_kernel(const float* __restrict__ deltaT,
                             const float* __restrict__ uT,
                             const float* __restrict__ xdblT,
                             const float* __restrict__ A_log,
                             float* __restrict__ Pa,
                             float* __restrict__ Sa) {
    int b = blockIdx.x >> 4;            // 0..7
    int dg = blockIdx.x & 15;           // 0..15 (64 d's per block)
    int c = blockIdx.y;                 // 0..14
    int t = threadIdx.x;
    int dgrp = t >> 4, n = t & 15;
    int d0 = dg * 64 + dgrp;            // chains at d0 + 16*vd

    float A[4], P[4], S[4];
    const float *pd[4], *pu[4];
    #pragma unroll
    for (int vd = 0; vd < 4; ++vd) {
        int d = d0 + 16 * vd;
        A[vd] = -__expf(A_log[d * D_STATE + n]);
        P[vd] = 1.f; S[vd] = 0.f;
        size_t base = (size_t)d * PITCH + b * Lseq + c * CHUNK;
        pd[vd] = deltaT + base;
        pu[vd] = uT + base;
    }
    const float* pB = xdblT + (size_t)(DT_RANK + n) * PITCH + b * Lseq + c * CHUNK;

    const int NI = CHUNK / 4;           // 32 (even)
    float4 BvA, dvA[4], uvA[4];
    float4 BvB, dvB[4], uvB[4];

    BvA = *(const float4*)(pB);
    #pragma unroll
    for (int vd = 0; vd < 4; ++vd) {
        dvA[vd] = *(const float4*)(pd[vd]);
        uvA[vd] = *(const float4*)(pu[vd]);
    }

    for (int i = 0; i < NI; i += 2) {
        BvB = *(const float4*)(pB + 4 * (i + 1));
        #pragma unroll
        for (int vd = 0; vd < 4; ++vd) {
            dvB[vd] = *(const float4*)(pd[vd] + 4 * (i + 1));
            uvB[vd] = *(const float4*)(pu[vd] + 4 * (i + 1));
        }
        #pragma unroll
        for (int vd = 0; vd < 4; ++vd) {
            float a;
            a = __expf(dvA[vd].x * A[vd]); P[vd] *= a; S[vd] = a * S[vd] + (dvA[vd].x * uvA[vd].x) * BvA.x;
            a = __expf(dvA[vd].y * A[vd]); P[vd] *= a; S[vd] = a * S[vd] + (dvA[vd].y * uvA[vd].y) * BvA.y;
            a = __expf(dvA[vd].z * A[vd]); P[vd] *= a; S[vd] = a * S[vd] + (dvA[vd].z * uvA[vd].z) * BvA.z;
            a = __expf(dvA[vd].w * A[vd]); P[vd] *= a; S[vd] = a * S[vd] + (dvA[vd].w * uvA[vd].w) * BvA.w;
        }
        int i2 = (i + 2 < NI) ? (i + 2) : (NI - 1);
        BvA = *(const float4*)(pB + 4 * i2);
        #pragma unroll
        for (int vd = 0; vd < 4; ++vd) {
            dvA[vd] = *(const float4*)(pd[vd] + 4 * i2);
            uvA[vd] = *(const float4*)(pu[vd] + 4 * i2);
        }
        #pragma unroll
        for (int vd = 0; vd < 4; ++vd) {
            float a;
            a = __expf(dvB[vd].x * A[vd]); P[vd] *= a; S[vd] = a * S[vd] + (dvB[vd].x * uvB[vd].x) * BvB.x;
            a = __expf(dvB[vd].y * A[vd]); P[vd] *= a; S[vd] = a * S[vd] + (dvB[vd].y * uvB[vd].y) * BvB.y;
            a = __expf(dvB[vd].z * A[vd]); P[vd] *= a; S[vd] = a * S[vd] + (dvB[vd].z * uvB[vd].z) * BvB.z;
            a = __expf(dvB[vd].w * A[vd]); P[vd] *= a; S[vd] = a * S[vd] + (dvB[vd].w * uvB[vd].w) * BvB.w;
        }
    }
    #pragma unroll
    for (int vd = 0; vd < 4; ++vd) {
        int d = d0 + 16 * vd;
        size_t o = ((size_t)(b * NCHUNK_A + c) * D_INNER + d) * 16 + n;
        Pa[o] = P[vd];
        Sa[o] = S[vd];
    }
}

// ---------------------------------------------------------------------------
// 6b) Chunked scan, pass B: combine chunk factors, scan final chunk, emit y.
// ---------------------------------------------------------------------------
__launch_bounds__(256)
__global__ void scanB_kernel(const float* __restrict__ deltaT,
                             const float* __restrict__ uT,
                             const float* __restrict__ xdblT,
                             const float* __restrict__ A_log,
                             const float* __restrict__ Dp,
                             const float* __restrict__ Pa,
                             const float* __restrict__ Sa,
                             const float* __restrict__ z96,
                             float* __restrict__ y96) {
    int b = blockIdx.x >> 6;
    int dg = blockIdx.x & 63;
    int t = threadIdx.x;
    int d = dg * 16 + (t >> 4);
    int n = t & 15;
    float A = -__expf(A_log[d * D_STATE + n]);
    float Dd = Dp[d];
    float h = 0.f;
    for (int c = 0; c < NCHUNK_A; ++c) {
        size_t o = ((size_t)(b * NCHUNK_A + c) * D_INNER + d) * 16 + n;
        h = Pa[o] * h + Sa[o];
    }
    const int lt0 = NCHUNK_A * CHUNK;     // 1920
    size_t base = (size_t)d * PITCH + b * Lseq + lt0;
    const float* pd = deltaT + base;
    const float* pu = uT + base;
    const float* pB = xdblT + (size_t)(DT_RANK + n) * PITCH + b * Lseq + lt0;
    const float* pC = xdblT + (size_t)(DT_RANK + D_STATE + n) * PITCH + b * Lseq + lt0;

    #pragma unroll 2
    for (int i = 0; i < 8; ++i) {
        float4 dv = *(const float4*)(pd + 4 * i);
        float4 uv = *(const float4*)(pu + 4 * i);
        float4 Bv = *(const float4*)(pB + 4 * i);
        float a;
        a = __expf(dv.x * A); h = a * h + (dv.x * uv.x) * Bv.x;
        a = __expf(dv.y * A); h = a * h + (dv.y * uv.y) * Bv.y;
        a = __expf(dv.z * A); h = a * h + (dv.z * uv.z) * Bv.z;
        a = __expf(dv.w * A); h = a * h + (dv.w * uv.w) * Bv.w;
    }
    for (int i = 8; i < 32; ++i) {
        float4 dv = *(const float4*)(pd + 4 * i);
        float4 uv = *(const float4*)(pu + 4 * i);
        float4 Bv = *(const float4*)(pB + 4 * i);
        float4 Cv = *(const float4*)(pC + 4 * i);
        #pragma unroll
        for (int j = 0; j < 4; ++j) {
            float dl = (j == 0) ? dv.x : (j == 1) ? dv.y : (j == 2) ? dv.z : dv.w;
            float uu = (j == 0) ? uv.x : (j == 1) ? uv.y : (j == 2) ? uv.z : uv.w;
            float Bb = (j == 0) ? Bv.x : (j == 1) ? Bv.y : (j == 2) ? Bv.z : Bv.w;
            float Cc = (j == 0) ? Cv.x : (j == 1) ? Cv.y : (j == 2) ? Cv.z : Cv.w;
            float a = __expf(dl * A);
            h = a * h + (dl * uu) * Bb;
            float y = h * Cc;
            #pragma unroll
            for (int m = 8; m >= 1; m >>= 1) y += __shfl_xor(y, m, 16);
            if (n == 0) {
                int lz = (lt0 + 4 * i + j) - L_TAIL;   // 0..95
                size_t o = ((size_t)b * PRED_LEN + lz) * D_INNER + d;
                float z = z96[o];
                y96[o] = (y + uu * Dd) * (z / (1.f + __expf(-z)));
            }
        }
    }
}

// ---------------------------------------------------------------------------
// 7) Final head: out[b,t,c] = (y96[b,t,:] . W[c,:]) * std[b,c] + mean[b,c]
// ---------------------------------------------------------------------------
__global__ void head_kernel(const float* __restrict__ y96,
                            const float* __restrict__ W,
                            const float* __restrict__ mean,
                            const float* __restrict__ stdv,
                            float* __restrict__ out) {
    int idx = blockIdx.x;                 // 8*96*21
    int c = idx % C_OUT;
    int bt = idx / C_OUT;
    int b = bt / PRED_LEN;
    int lane = threadIdx.x;
    const float* yrow = y96 + (size_t)bt * D_INNER;
    const float* wrow = W + (size_t)c * D_INNER;
    float s = 0.f;
    for (int d = lane; d < D_INNER; d += 64) s += yrow[d] * wrow[d];
    #pragma unroll
    for (int m = 32; m >= 1; m >>= 1) s += __shfl_xor(s, m, 64);
    if (lane == 0)
        out[(size_t)bt * C_OUT + c] = s * stdv[b * C_OUT + c] + mean[b * C_OUT + c];
}

// ---------------------------------------------------------------------------
extern "C" void kernel_launch(void* const* d_in, const int* in_sizes, int n_in,
                              void* d_out, int out_size, void* d_ws, size_t ws_size,
                              hipStream_t stream) {
    const float* x_enc     = (const float*)d_in[0];
    const float* x_mark    = (const float*)d_in[1];
    const float* conv_w    = (const float*)d_in[4];
    const float* temp_w    = (const float*)d_in[5];
    const float* in_proj_w = (const float*)d_in[6];
    const float* conv1d_w  = (const float*)d_in[7];
    const float* conv1d_b  = (const float*)d_in[8];
    const float* x_proj_w  = (const float*)d_in[9];
    const float* dt_proj_w = (const float*)d_in[10];
    const float* dt_proj_b = (const float*)d_in[11];
    const float* A_log     = (const float*)d_in[12];
    const float* Dp        = (const float*)d_in[13];
    const float* out_proj_w= (const float*)d_in[14];
    const float* head_w    = (const float*)d_in[15];
    float* out = (float*)d_out;
    float* ws = (float*)d_ws;

    // workspace layout (floats) — NO aliasing. (xs_rawT removed: conv fused)
    size_t off = 0;
    float* mean     = ws + off; off += 256;
    float* stdv     = ws + off; off += 256;
    float* W        = ws + off; off += (size_t)C_OUT * D_INNER;            // 21504
    float* WembT    = ws + off; off += (size_t)K_EMB * D_MODEL;            // 40960
    float* Wcomb    = ws + off; off += (size_t)2 * D_INNER * K_EMB;        // 163840
    float* PEpT     = ws + off; off += (size_t)D_INNER * Lseq;             // 2.10M
    float* PEpZ     = ws + off; off += (size_t)PRED_LEN * D_INNER;         // 98304
    float* xin      = ws + off; off += (size_t)K_EMB * MTOT;               // 1.31M
    float* z96      = ws + off; off += (size_t)Bsz * PRED_LEN * D_INNER;   // 0.79M
    float* xs_convT = ws + off; off += (size_t)D_INNER * PITCH;            // 16.8M
    float* xdblT    = ws + off; off += (size_t)64 * PITCH;                 // 1.05M
    float* deltaT   = ws + off; off += (size_t)D_INNER * PITCH;            // 16.8M
    float* Pa       = ws + off; off += (size_t)Bsz * NCHUNK_A * D_INNER * D_STATE; // 1.97M
    float* Sa       = ws + off; off += (size_t)Bsz * NCHUNK_A * D_INNER * D_STATE; // 1.97M
    float* y96      = ws + off; off += (size_t)Bsz * PRED_LEN * D_INNER;   // 0.79M
    float* xdbl_rm  = ws + off; off += (size_t)MTOT * DT_RANK;             // 0.52M

    // 1) instance-norm stats (one pass)
    stats_kernel<<<Bsz * ENC_IN, 256, 0, stream>>>(x_enc, mean, stdv);
    // 2) fused output weight
    fuse_w_kernel<<<(C_OUT * D_INNER + 255) / 256, 256, 0, stream>>>(head_w, out_proj_w, W);
    // 3) precomputations
    prep_wT_kernel<<<(K_EMB * D_MODEL) / 256, 256, 0, stream>>>(conv_w, temp_w, WembT);
    prep_x_kernel<<<(MTOT * K_EMB) / 256, 256, 0, stream>>>(x_enc, x_mark, mean, stdv, xin);
    wcomb_kernel<<<(2 * D_INNER * K_EMB) / 256, 256, 0, stream>>>(in_proj_w, WembT, Wcomb);
    pepz_kernel<<<dim3(PRED_LEN, 4), 256, 0, stream>>>(in_proj_w, PEpZ);
    // PEpT[j][l] = in_proj_xs @ pe^T  (MFMA 64-tile, analytic B; 512 blocks)
    mfma_gemm64<1, 0><<<dim3(Lseq / 64, D_INNER / 64), 256, 0, stream>>>(
        in_proj_w, nullptr, PEpT, nullptr, D_INNER, Lseq, D_MODEL, D_MODEL, 0, Lseq);
    // 4a) xs_convT = silu(conv1d(Wcomb_xs @ xin^T + PEpT))  (MFMA, FUSED conv)
    mfma_gemm128<2, 3><<<dim3(MTOT / 64, D_INNER / 128), 256, 0, stream>>>(
        Wcomb, xin, xs_convT, PEpT, conv1d_w, conv1d_b,
        D_INNER, MTOT, K_EMB, K_EMB, K_EMB, PITCH);
    // 4b) z96[bt][d] = xin[tail-remap] @ Wcomb_z^T + PEpZ[bt%96][d]  (fp32)
    gemm<3, 0, 3><<<dim3(D_INNER / 64, (Bsz * PRED_LEN) / 64), 256, 0, stream>>>(
        xin, Wcomb + (size_t)D_INNER * K_EMB, z96, PEpZ,
        Bsz * PRED_LEN, D_INNER, K_EMB, K_EMB, K_EMB);
    // 6) xdblT[p][bl] = x_proj_w @ xs_convT  (split-K x4, atomic accumulate)
    zero_kernel<<<(64 * PITCH) / 4 / 256, 256, 0, stream>>>((float4*)xdblT);
    mfma_gemm_splitk<<<dim3(MTOT / 64, 1, 4), 256, 0, stream>>>(
        x_proj_w, xs_convT, xdblT, 64, MTOT, D_INNER, D_INNER, PITCH, PITCH, 256);
    // 6b) transpose rank rows -> xdbl_rm[bl][32]
    xdbl_tr_kernel<<<MTOT / 64, 256, 0, stream>>>(xdblT, xdbl_rm);
    // 7) deltaT[d][bl] = softplus(dt_proj_w @ xdbl_rm^T + dt_b[d])  (MFMA)
    mfma_gemm128<2, 1><<<dim3(MTOT / 64, D_INNER / 128), 256, 0, stream>>>(
        dt_proj_w, xdbl_rm, deltaT, dt_proj_b, nullptr, nullptr,
        D_INNER, MTOT, DT_RANK, DT_RANK, DT_RANK, PITCH);
    // 8) chunked selective scan (R13 4-chain pass A)
    scanA_kernel<<<dim3(Bsz * 16, NCHUNK_A), 256, 0, stream>>>(
        deltaT, xs_convT, xdblT, A_log, Pa, Sa);
    scanB_kernel<<<Bsz * 64, 256, 0, stream>>>(
        deltaT, xs_convT, xdblT, A_log, Dp, Pa, Sa, z96, y96);
    // 9) head + de-normalize
    head_kernel<<<Bsz * PRED_LEN * C_OUT, 64, 0, stream>>>(y96, W, mean, stdv, out);
}

// Round 18
// 456.020 us; speedup vs baseline: 1.0130x; 1.0130x over previous
//
#include <hip/hip_runtime.h>
#include <hip/hip_bf16.h>
#include <math.h>

// Problem constants
#define Bsz 8
#define Lseq 2048
#define ENC_IN 21
#define C_OUT 21
#define D_MODEL 512
#define D_INNER 1024
#define D_STATE 16
#define D_CONV 4
#define DT_RANK 32
#define MARK_DIM 4
#define PRED_LEN 96
#define L_TAIL (Lseq - PRED_LEN)   // 1952
#define K_EMB 80                   // 63 conv taps + 4 mark + 13 zero-pad
#define CHUNK 128
#define NCHUNK_A 15                // chunks 0..14 in pass A; chunk 15 in pass B
#define MTOT (Bsz * Lseq)          // 16384
#define PITCH (MTOT + 16)          // 16400 floats (65600 B rows)

#define PE_C0 (-9.210340371976184f / (float)D_MODEL)   // -ln(10000)/d_model

typedef __attribute__((ext_vector_type(8))) short short8;
typedef __attribute__((ext_vector_type(4))) float f32x4;

// ---------------------------------------------------------------------------
// 1) Instance-norm stats: one-pass mean/std per (b, c)
// ---------------------------------------------------------------------------
__global__ void stats_kernel(const float* __restrict__ x_enc,
                             float* __restrict__ mean, float* __restrict__ stdv) {
    int bc = blockIdx.x;               // 0..167
    int b = bc / ENC_IN, c = bc % ENC_IN;
    __shared__ float red[256], red2[256];
    int t = threadIdx.x;
    float s = 0.f, s2 = 0.f;
    for (int l = t; l < Lseq; l += 256) {
        float x = x_enc[((size_t)b * Lseq + l) * ENC_IN + c];
        s += x; s2 += x * x;
    }
    red[t] = s; red2[t] = s2; __syncthreads();
    for (int off = 128; off > 0; off >>= 1) {
        if (t < off) { red[t] += red[t + off]; red2[t] += red2[t + off]; }
        __syncthreads();
    }
    if (t == 0) {
        float m = red[0] / (float)Lseq;
        float v = red2[0] / (float)Lseq - m * m;
        mean[bc] = m;
        stdv[bc] = sqrtf(fmaxf(v, 0.f) + 1e-5f);
    }
}

// ---------------------------------------------------------------------------
// 2) Fuse head_w @ out_proj_w -> W (21 x 1024)
// ---------------------------------------------------------------------------
__global__ void fuse_w_kernel(const float* __restrict__ head_w,
                              const float* __restrict__ out_proj_w,
                              float* __restrict__ W) {
    int idx = blockIdx.x * 256 + threadIdx.x;
    if (idx >= C_OUT * D_INNER) return;
    int c = idx / D_INNER, d = idx % D_INNER;
    float s = 0.f;
    for (int k = 0; k < D_MODEL; ++k)
        s += head_w[c * D_MODEL + k] * out_proj_w[(size_t)k * D_INNER + d];
    W[idx] = s;
}

// ---------------------------------------------------------------------------
// 3a) Pack embedding weights TRANSPOSED: WembT[k][d]
// ---------------------------------------------------------------------------
__global__ void prep_wT_kernel(const float* __restrict__ conv_w,
                               const float* __restrict__ temp_w,
                               float* __restrict__ WembT) {
    int idx = blockIdx.x * 256 + threadIdx.x;        // 80*512 exact
    int k = idx / D_MODEL, d = idx % D_MODEL;
    float v = 0.f;
    if (k < 3 * ENC_IN) {
        int kk = k / ENC_IN, c = k % ENC_IN;
        v = conv_w[((size_t)d * ENC_IN + c) * 3 + kk];
    } else if (k < 3 * ENC_IN + MARK_DIM) {
        v = temp_w[d * MARK_DIM + (k - 3 * ENC_IN)];
    }
    WembT[idx] = v;
}

// ---------------------------------------------------------------------------
// 3b) Build xin[bl][k] ROW-MAJOR
// ---------------------------------------------------------------------------
__global__ void prep_x_kernel(const float* __restrict__ x_enc,
                              const float* __restrict__ x_mark,
                              const float* __restrict__ mean,
                              const float* __restrict__ stdv,
                              float* __restrict__ xin) {
    int idx = blockIdx.x * 256 + threadIdx.x;        // 16384*80 exact
    int bl = idx / K_EMB, k = idx % K_EMB;
    int b = bl >> 11, l = bl & (Lseq - 1);
    float v = 0.f;
    if (k < 3 * ENC_IN) {
        int kk = k / ENC_IN, c = k % ENC_IN;
        int ll = (l + kk - 1 + Lseq) & (Lseq - 1);
        v = (x_enc[((size_t)b * Lseq + ll) * ENC_IN + c] - mean[b * ENC_IN + c])
            / stdv[b * ENC_IN + c];
    } else if (k < 3 * ENC_IN + MARK_DIM) {
        v = x_mark[((size_t)b * Lseq + l) * MARK_DIM + (k - 3 * ENC_IN)];
    }
    xin[idx] = v;
}

// ---------------------------------------------------------------------------
// 3c) Wcomb[j][k] = sum_d in_proj_w[j][d] * WembT[k][d]   (2048 x 80)
// ---------------------------------------------------------------------------
__global__ void wcomb_kernel(const float* __restrict__ in_proj_w,
                             const float* __restrict__ WembT,
                             float* __restrict__ Wcomb) {
    int idx = blockIdx.x * 256 + threadIdx.x;        // 2048*80 exact
    int j = idx / K_EMB, k = idx % K_EMB;
    const float* a = in_proj_w + (size_t)j * D_MODEL;
    const float* b = WembT + (size_t)k * D_MODEL;
    float s = 0.f;
    for (int d = 0; d < D_MODEL; d += 4) {
        float4 av = *(const float4*)(a + d);
        float4 bv = *(const float4*)(b + d);
        s += av.x * bv.x + av.y * bv.y + av.z * bv.z + av.w * bv.w;
    }
    Wcomb[idx] = s;
}

// ---------------------------------------------------------------------------
// 3d) PEpZ[lz][j] = pe[1952+lz][:] . in_proj_w[1024+j][:]  (96 x 1024)
// ---------------------------------------------------------------------------
__global__ void pepz_kernel(const float* __restrict__ in_proj_w,
                            float* __restrict__ PEpZ) {
    __shared__ float per[D_MODEL];
    int lz = blockIdx.x;                  // 0..95
    int q = blockIdx.y;                   // 0..3
    int t = threadIdx.x;
    {
        int l = L_TAIL + lz;
        float div = __expf((float)(2 * t) * PE_C0);
        float s, c;
        sincosf((float)l * div, &s, &c);
        per[2 * t] = s;
        per[2 * t + 1] = c;
    }
    __syncthreads();
    int j = q * 256 + t;
    const float* w = in_proj_w + (size_t)(D_INNER + j) * D_MODEL;
    float s = 0.f;
    for (int d = 0; d < D_MODEL; d += 4) {
        float4 wv = *(const float4*)(w + d);
        s += per[d] * wv.x + per[d + 1] * wv.y + per[d + 2] * wv.z + per[d + 3] * wv.w;
    }
    PEpZ[(size_t)lz * D_INNER + j] = s;
}

// ---------------------------------------------------------------------------
// 4a) Small fp32 GEMM (z96 tail slice).
// ---------------------------------------------------------------------------
template <int AMODE, int BMODE, int EPI>
__launch_bounds__(256)
__global__ void gemm(const float* __restrict__ A, const float* __restrict__ B,
                     float* __restrict__ C0, const float* __restrict__ bias,
                     int M, int N, int K, int lda, int ldb) {
    __shared__ float As[16][65];
    __shared__ float Bs[16][65];
    int bm = blockIdx.y, bn = blockIdx.x;
    int t = threadIdx.x;
    int tx = t & 15, ty = t >> 4;
    float acc[4][4] = {};
    int arow = bm * 64, bcol = bn * 64;
    int lr = t >> 2;
    int lk = (t & 3) * 4;

    size_t aRow;
    {
        int r = arow + lr;
        if (AMODE == 3) {
            int rb = r / PRED_LEN;
            int rl = r - rb * PRED_LEN;
            aRow = (size_t)rb * Lseq + L_TAIL + rl;
        } else {
            aRow = (size_t)r;
        }
    }

    for (int k0 = 0; k0 < K; k0 += 16) {
        {
            float4 av = *(const float4*)(A + aRow * lda + k0 + lk);
            As[lk + 0][lr] = av.x; As[lk + 1][lr] = av.y;
            As[lk + 2][lr] = av.z; As[lk + 3][lr] = av.w;
        }
        {
            float4 bv = *(const float4*)(B + (size_t)(bcol + lr) * ldb + k0 + lk);
            Bs[lk + 0][lr] = bv.x; Bs[lk + 1][lr] = bv.y;
            Bs[lk + 2][lr] = bv.z; Bs[lk + 3][lr] = bv.w;
        }
        __syncthreads();
        #pragma unroll
        for (int kk = 0; kk < 16; ++kk) {
            float a[4], bq[4];
            #pragma unroll
            for (int i = 0; i < 4; ++i) a[i] = As[kk][ty * 4 + i];
            #pragma unroll
            for (int j = 0; j < 4; ++j) bq[j] = Bs[kk][tx * 4 + j];
            #pragma unroll
            for (int i = 0; i < 4; ++i)
                #pragma unroll
                for (int j = 0; j < 4; ++j)
                    acc[i][j] += a[i] * bq[j];
        }
        __syncthreads();
    }

    #pragma unroll
    for (int i = 0; i < 4; ++i) {
        int row = arow + ty * 4 + i;
        #pragma unroll
        for (int j = 0; j < 4; ++j) {
            int col = bcol + tx * 4 + j;
            float v = acc[i][j];
            if (EPI == 3) {
                v += bias[(size_t)(row % PRED_LEN) * N + col];
            }
            C0[(size_t)row * N + col] = v;
        }
    }
}

// ---------------------------------------------------------------------------
// helper: fp32 -> (hi, lo) bf16 bit patterns (truncation split)
// ---------------------------------------------------------------------------
__device__ __forceinline__ void split_bf16(float x, short& hb, short& lb) {
    unsigned u = __float_as_uint(x);
    unsigned short h = (unsigned short)(u >> 16);
    float hf = __uint_as_float(((unsigned)h) << 16);
    unsigned short l = (unsigned short)(__float_as_uint(x - hf) >> 16);
    hb = (short)h; lb = (short)l;
}

// ---------------------------------------------------------------------------
// 4b) Split-bf16 MFMA GEMM, 128(M) x 64(N) tile, K-step 32, 4 waves.
//     BMODE 0: B k-major  BMODE 1: analytic PE  BMODE 2: B row-major [n][k]
//     EPI 0: none   1: +bias[row], softplus   2: +bias[row*2048+(col&2047)]
// ---------------------------------------------------------------------------
template <int BMODE, int EPI>
__launch_bounds__(256)
__global__ void mfma_gemm128(const float* __restrict__ A, const float* __restrict__ B,
                             float* __restrict__ C, const float* __restrict__ bias,
                             int M, int N, int K, int lda, int ldb, int ldc) {
    __shared__ short Ah[128][48], Al[128][48];
    __shared__ short Bh[64][48], Bl[64][48];
    int t = threadIdx.x;
    int bn0 = blockIdx.x * 64;
    int am0 = blockIdx.y * 128;
    int w = t >> 6, l = t & 63;
    int lr = l & 15, lk = l >> 4;

    f32x4 acc[2][4];
    #pragma unroll
    for (int i = 0; i < 2; ++i)
        #pragma unroll
        for (int j = 0; j < 4; ++j) acc[i][j] = (f32x4){0.f, 0.f, 0.f, 0.f};

    const int mst = t >> 2, kst = (t & 3) * 8;

    for (int kb = 0; kb < K; kb += 32) {
        if (kb) __syncthreads();
        #pragma unroll
        for (int half = 0; half < 2; ++half) {
            int m = mst + half * 64;
            const float* src = A + (size_t)(am0 + m) * lda + kb + kst;
            short8 hv, lv;
            if (kb + 32 <= K) {
                float4 a0 = *(const float4*)(src);
                float4 a1 = *(const float4*)(src + 4);
                float xs[8] = {a0.x, a0.y, a0.z, a0.w, a1.x, a1.y, a1.z, a1.w};
                #pragma unroll
                for (int j = 0; j < 8; ++j) {
                    short hb, lb; split_bf16(xs[j], hb, lb);
                    hv[j] = hb; lv[j] = lb;
                }
            } else {
                #pragma unroll
                for (int j = 0; j < 8; ++j) {
                    float x = (kb + kst + j < K) ? src[j] : 0.f;
                    short hb, lb; split_bf16(x, hb, lb);
                    hv[j] = hb; lv[j] = lb;
                }
            }
            *(short8*)&Ah[m][kst] = hv;
            *(short8*)&Al[m][kst] = lv;
        }
        if constexpr (BMODE == 0) {
            short8 hv, lv;
            #pragma unroll
            for (int j = 0; j < 8; ++j) {
                int k = kb + kst + j;
                float x = (k < K) ? B[(size_t)k * ldb + bn0 + mst] : 0.f;
                short hb, lb; split_bf16(x, hb, lb);
                hv[j] = hb; lv[j] = lb;
            }
            *(short8*)&Bh[mst][kst] = hv;
            *(short8*)&Bl[mst][kst] = lv;
        } else if constexpr (BMODE == 1) {
            float ng = (float)(bn0 + mst);
            short8 hv, lv;
            #pragma unroll
            for (int p = 0; p < 4; ++p) {
                float e = __expf((float)(kb + kst + 2 * p) * PE_C0);
                float sv, cv;
                sincosf(ng * e, &sv, &cv);
                short hb, lb;
                split_bf16(sv, hb, lb); hv[2 * p] = hb; lv[2 * p] = lb;
                split_bf16(cv, hb, lb); hv[2 * p + 1] = hb; lv[2 * p + 1] = lb;
            }
            *(short8*)&Bh[mst][kst] = hv;
            *(short8*)&Bl[mst][kst] = lv;
        } else {
            const float* src = B + (size_t)(bn0 + mst) * ldb + kb + kst;
            short8 hv, lv;
            if (kb + 32 <= K) {
                float4 b0 = *(const float4*)(src);
                float4 b1 = *(const float4*)(src + 4);
                float xs[8] = {b0.x, b0.y, b0.z, b0.w, b1.x, b1.y, b1.z, b1.w};
                #pragma unroll
                for (int j = 0; j < 8; ++j) {
                    short hb, lb; split_bf16(xs[j], hb, lb);
                    hv[j] = hb; lv[j] = lb;
                }
            } else {
                #pragma unroll
                for (int j = 0; j < 8; ++j) {
                    float x = (kb + kst + j < K) ? src[j] : 0.f;
                    short hb, lb; split_bf16(x, hb, lb);
                    hv[j] = hb; lv[j] = lb;
                }
            }
            *(short8*)&Bh[mst][kst] = hv;
            *(short8*)&Bl[mst][kst] = lv;
        }
        __syncthreads();
        #pragma unroll
        for (int mt = 0; mt < 2; ++mt) {
            short8 a_hi = *(const short8*)&Ah[mt * 64 + w * 16 + lr][lk * 8];
            short8 a_lo = *(const short8*)&Al[mt * 64 + w * 16 + lr][lk * 8];
            #pragma unroll
            for (int t4 = 0; t4 < 4; ++t4) {
                short8 b_hi = *(const short8*)&Bh[t4 * 16 + lr][lk * 8];
                short8 b_lo = *(const short8*)&Bl[t4 * 16 + lr][lk * 8];
                acc[mt][t4] = __builtin_amdgcn_mfma_f32_16x16x32_bf16(a_hi, b_hi, acc[mt][t4], 0, 0, 0);
                acc[mt][t4] = __builtin_amdgcn_mfma_f32_16x16x32_bf16(a_lo, b_hi, acc[mt][t4], 0, 0, 0);
                acc[mt][t4] = __builtin_amdgcn_mfma_f32_16x16x32_bf16(a_hi, b_lo, acc[mt][t4], 0, 0, 0);
            }
        }
    }

    #pragma unroll
    for (int mt = 0; mt < 2; ++mt) {
        #pragma unroll
        for (int t4 = 0; t4 < 4; ++t4) {
            #pragma unroll
            for (int r = 0; r < 4; ++r) {
                int row = am0 + mt * 64 + w * 16 + lk * 4 + r;
                int col = bn0 + t4 * 16 + lr;
                float v = acc[mt][t4][r];
                if (EPI == 1) {
                    v += bias[row];
                    v = (v > 20.f) ? v : log1pf(__expf(v));
                }
                if (EPI == 2) {
                    v += bias[(size_t)row * Lseq + (col & (Lseq - 1))];
                }
                C[(size_t)row * ldc + col] = v;
            }
        }
    }
}

// ---------------------------------------------------------------------------
// 4b') Split-bf16 MFMA GEMM, 64(M) x 64(N) tile — PEpT. BMODE 1: analytic PE.
// ---------------------------------------------------------------------------
template <int BMODE, int EPI>
__launch_bounds__(256)
__global__ void mfma_gemm64(const float* __restrict__ A, const float* __restrict__ B,
                            float* __restrict__ C, const float* __restrict__ bias,
                            int M, int N, int K, int lda, int ldb, int ldc) {
    __shared__ short Ah[64][48], Al[64][48];
    __shared__ short Bh[64][48], Bl[64][48];
    int t = threadIdx.x;
    int bn0 = blockIdx.x * 64;
    int am0 = blockIdx.y * 64;
    int w = t >> 6, l = t & 63;
    int lr = l & 15, lk = l >> 4;

    f32x4 acc[4];
    #pragma unroll
    for (int i = 0; i < 4; ++i) acc[i] = (f32x4){0.f, 0.f, 0.f, 0.f};

    const int mst = t >> 2, kst = (t & 3) * 8;

    for (int kb = 0; kb < K; kb += 32) {
        if (kb) __syncthreads();
        {
            const float* src = A + (size_t)(am0 + mst) * lda + kb + kst;
            short8 hv, lv;
            if (kb + 32 <= K) {
                float4 a0 = *(const float4*)(src);
                float4 a1 = *(const float4*)(src + 4);
                float xs[8] = {a0.x, a0.y, a0.z, a0.w, a1.x, a1.y, a1.z, a1.w};
                #pragma unroll
                for (int j = 0; j < 8; ++j) {
                    short hb, lb; split_bf16(xs[j], hb, lb);
                    hv[j] = hb; lv[j] = lb;
                }
            } else {
                #pragma unroll
                for (int j = 0; j < 8; ++j) {
                    float x = (kb + kst + j < K) ? src[j] : 0.f;
                    short hb, lb; split_bf16(x, hb, lb);
                    hv[j] = hb; lv[j] = lb;
                }
            }
            *(short8*)&Ah[mst][kst] = hv;
            *(short8*)&Al[mst][kst] = lv;
        }
        if constexpr (BMODE == 1) {
            float ng = (float)(bn0 + mst);
            short8 hv, lv;
            #pragma unroll
            for (int p = 0; p < 4; ++p) {
                float e = __expf((float)(kb + kst + 2 * p) * PE_C0);
                float sv, cv;
                sincosf(ng * e, &sv, &cv);
                short hb, lb;
                split_bf16(sv, hb, lb); hv[2 * p] = hb; lv[2 * p] = lb;
                split_bf16(cv, hb, lb); hv[2 * p + 1] = hb; lv[2 * p + 1] = lb;
            }
            *(short8*)&Bh[mst][kst] = hv;
            *(short8*)&Bl[mst][kst] = lv;
        } else {
            short8 hv, lv;
            #pragma unroll
            for (int j = 0; j < 8; ++j) {
                int k = kb + kst + j;
                float x = (k < K) ? B[(size_t)k * ldb + bn0 + mst] : 0.f;
                short hb, lb; split_bf16(x, hb, lb);
                hv[j] = hb; lv[j] = lb;
            }
            *(short8*)&Bh[mst][kst] = hv;
            *(short8*)&Bl[mst][kst] = lv;
        }
        __syncthreads();
        short8 a_hi = *(const short8*)&Ah[w * 16 + lr][lk * 8];
        short8 a_lo = *(const short8*)&Al[w * 16 + lr][lk * 8];
        #pragma unroll
        for (int t4 = 0; t4 < 4; ++t4) {
            short8 b_hi = *(const short8*)&Bh[t4 * 16 + lr][lk * 8];
            short8 b_lo = *(const short8*)&Bl[t4 * 16 + lr][lk * 8];
            acc[t4] = __builtin_amdgcn_mfma_f32_16x16x32_bf16(a_hi, b_hi, acc[t4], 0, 0, 0);
            acc[t4] = __builtin_amdgcn_mfma_f32_16x16x32_bf16(a_lo, b_hi, acc[t4], 0, 0, 0);
            acc[t4] = __builtin_amdgcn_mfma_f32_16x16x32_bf16(a_hi, b_lo, acc[t4], 0, 0, 0);
        }
    }

    #pragma unroll
    for (int t4 = 0; t4 < 4; ++t4) {
        #pragma unroll
        for (int r = 0; r < 4; ++r) {
            int row = am0 + w * 16 + lk * 4 + r;
            int col = bn0 + t4 * 16 + lr;
            C[(size_t)row * ldc + col] = acc[t4][r];
        }
    }
}

// ---------------------------------------------------------------------------
// 4c) Split-K MFMA GEMM for x_proj (M=64), atomic accumulate (C pre-zeroed).
// ---------------------------------------------------------------------------
__launch_bounds__(256)
__global__ void mfma_gemm_splitk(const float* __restrict__ A, const float* __restrict__ B,
                                 float* __restrict__ C,
                                 int M, int N, int K, int lda, int ldb, int ldc,
                                 int ksplit) {
    __shared__ short Ah[64][48], Al[64][48];
    __shared__ short Bh[64][48], Bl[64][48];
    int t = threadIdx.x;
    int bn0 = blockIdx.x * 64;
    int kz0 = blockIdx.z * ksplit;
    int kz1 = min(K, kz0 + ksplit);
    int w = t >> 6, l = t & 63;
    int lr = l & 15, lk = l >> 4;

    f32x4 acc[4];
    #pragma unroll
    for (int i = 0; i < 4; ++i) acc[i] = (f32x4){0.f, 0.f, 0.f, 0.f};

    const int mst = t >> 2, kst = (t & 3) * 8;

    for (int kb = kz0; kb < kz1; kb += 32) {
        if (kb != kz0) __syncthreads();
        {
            const float* src = A + (size_t)mst * lda + kb + kst;
            float4 a0 = *(const float4*)(src);
            float4 a1 = *(const float4*)(src + 4);
            float xs[8] = {a0.x, a0.y, a0.z, a0.w, a1.x, a1.y, a1.z, a1.w};
            short8 hv, lv;
            #pragma unroll
            for (int j = 0; j < 8; ++j) {
                short hb, lb; split_bf16(xs[j], hb, lb);
                hv[j] = hb; lv[j] = lb;
            }
            *(short8*)&Ah[mst][kst] = hv;
            *(short8*)&Al[mst][kst] = lv;
        }
        {
            short8 hv, lv;
            #pragma unroll
            for (int j = 0; j < 8; ++j) {
                int k = kb + kst + j;
                float x = B[(size_t)k * ldb + bn0 + mst];
                short hb, lb; split_bf16(x, hb, lb);
                hv[j] = hb; lv[j] = lb;
            }
            *(short8*)&Bh[mst][kst] = hv;
            *(short8*)&Bl[mst][kst] = lv;
        }
        __syncthreads();
        short8 a_hi = *(const short8*)&Ah[w * 16 + lr][lk * 8];
        short8 a_lo = *(const short8*)&Al[w * 16 + lr][lk * 8];
        #pragma unroll
        for (int t4 = 0; t4 < 4; ++t4) {
            short8 b_hi = *(const short8*)&Bh[t4 * 16 + lr][lk * 8];
            short8 b_lo = *(const short8*)&Bl[t4 * 16 + lr][lk * 8];
            acc[t4] = __builtin_amdgcn_mfma_f32_16x16x32_bf16(a_hi, b_hi, acc[t4], 0, 0, 0);
            acc[t4] = __builtin_amdgcn_mfma_f32_16x16x32_bf16(a_lo, b_hi, acc[t4], 0, 0, 0);
            acc[t4] = __builtin_amdgcn_mfma_f32_16x16x32_bf16(a_hi, b_lo, acc[t4], 0, 0, 0);
        }
    }

    #pragma unroll
    for (int t4 = 0; t4 < 4; ++t4) {
        #pragma unroll
        for (int r = 0; r < 4; ++r) {
            int row = w * 16 + lk * 4 + r;
            int col = bn0 + t4 * 16 + lr;
            atomicAdd(&C[(size_t)row * ldc + col], acc[t4][r]);
        }
    }
}

// ---------------------------------------------------------------------------
// 4d) zero-init for the split-K output (xdblT, 64 x PITCH floats)
// ---------------------------------------------------------------------------
__global__ void zero_kernel(float4* __restrict__ p) {
    p[(size_t)blockIdx.x * 256 + threadIdx.x] = make_float4(0.f, 0.f, 0.f, 0.f);
}

// ---------------------------------------------------------------------------
// 4e) Transpose xdblT rank rows (32 x PITCH, k-major) -> xdbl_rm (MTOT x 32)
// ---------------------------------------------------------------------------
__global__ void xdbl_tr_kernel(const float* __restrict__ xdblT,
                               float* __restrict__ xdbl_rm) {
    __shared__ float tile[32][65];
    int l0 = blockIdx.x * 64;
    int t = threadIdx.x;
    {
        int p = t >> 3, ls = (t & 7) * 8;
        const float* src = xdblT + (size_t)p * PITCH + l0 + ls;
        float4 v0 = *(const float4*)(src);
        float4 v1 = *(const float4*)(src + 4);
        tile[p][ls + 0] = v0.x; tile[p][ls + 1] = v0.y;
        tile[p][ls + 2] = v0.z; tile[p][ls + 3] = v0.w;
        tile[p][ls + 4] = v1.x; tile[p][ls + 5] = v1.y;
        tile[p][ls + 6] = v1.z; tile[p][ls + 7] = v1.w;
    }
    __syncthreads();
    {
        int ll = t >> 2, ps = (t & 3) * 8;
        float o[8];
        #pragma unroll
        for (int j = 0; j < 8; ++j) o[j] = tile[ps + j][ll];
        float* dst = xdbl_rm + (size_t)(l0 + ll) * DT_RANK + ps;
        *(float4*)(dst)     = make_float4(o[0], o[1], o[2], o[3]);
        *(float4*)(dst + 4) = make_float4(o[4], o[5], o[6], o[7]);
    }
}

// ---------------------------------------------------------------------------
// 5) Depthwise causal conv1d (k=4) + SiLU.
//    Reads xs_rawT (pitch MTOT), writes xs_convT (pitch PITCH).
// ---------------------------------------------------------------------------
__global__ void dwconv_kernel(const float* __restrict__ xs_rawT,
                              const float* __restrict__ w,
                              const float* __restrict__ bias,
                              float* __restrict__ outT) {
    int bid = blockIdx.x;                 // 1024 d * 16 chunks
    int d = bid & (D_INNER - 1), ch = bid >> 10;
    int t = threadIdx.x;
    int lbase = ch * 1024 + t * 4;
    const float* row = xs_rawT + (size_t)d * MTOT;
    float w0 = w[d * D_CONV + 0], w1 = w[d * D_CONV + 1];
    float w2 = w[d * D_CONV + 2], w3 = w[d * D_CONV + 3];
    float bs = bias[d];
    float4 cur = *(const float4*)(row + lbase);
    float4 pv = make_float4(0.f, 0.f, 0.f, 0.f);
    if (lbase >= 4) pv = *(const float4*)(row + lbase - 4);
    float v[7] = {pv.y, pv.z, pv.w, cur.x, cur.y, cur.z, cur.w};
    int lpos = lbase & (Lseq - 1);
    float o[4];
    if (lpos != 0) {
        #pragma unroll
        for (int j = 0; j < 4; ++j)
            o[j] = bs + w0 * v[j] + w1 * v[j + 1] + w2 * v[j + 2] + w3 * v[j + 3];
    } else {
        #pragma unroll
        for (int j = 0; j < 4; ++j) {
            float acc = bs;
            #pragma unroll
            for (int k2 = 0; k2 < 4; ++k2) {
                int ll = j - 3 + k2;
                if (ll >= 0) acc += v[j + k2] * ((k2 == 0) ? w0 : (k2 == 1) ? w1 : (k2 == 2) ? w2 : w3);
            }
            o[j] = acc;
        }
    }
    float4 res;
    res.x = o[0] / (1.f + __expf(-o[0]));
    res.y = o[1] / (1.f + __expf(-o[1]));
    res.z = o[2] / (1.f + __expf(-o[2]));
    res.w = o[3] / (1.f + __expf(-o[3]));
    *(float4*)(outT + (size_t)d * PITCH + lbase) = res;
}

// ---------------------------------------------------------------------------
// 6a) Chunked scan, pass A — R13-proven 4-chain version (per-wave working
//     set ~16KB, under L1 capacity; 8-chain variants thrash, see R11/R15).
// ---------------------------------------------------------------------------
__launch_bounds__(256, 4)
__global__ void scanA_kernel(const float* __restrict__ deltaT,
                             const float* __restrict__ uT,
                             const float* __restrict__ xdblT,
                             const float* __restrict__ A_log,
                             float* __restrict__ Pa,
                             float* __restrict__ Sa) {
    int b = blockIdx.x >> 4;            // 0..7
    int dg = blockIdx.x & 15;           // 0..15 (64 d's per block)
    int c = blockIdx.y;                 // 0..14
    int t = threadIdx.x;
    int dgrp = t >> 4, n = t & 15;
    int d0 = dg * 64 + dgrp;            // chains at d0 + 16*vd

    float A[4], P[4], S[4];
    const float *pd[4], *pu[4];
    #pragma unroll
    for (int vd = 0; vd < 4; ++vd) {
        int d = d0 + 16 * vd;
        A[vd] = -__expf(A_log[d * D_STATE + n]);
        P[vd] = 1.f; S[vd] = 0.f;
        size_t base = (size_t)d * PITCH + b * Lseq + c * CHUNK;
        pd[vd] = deltaT + base;
        pu[vd] = uT + base;
    }
    const float* pB = xdblT + (size_t)(DT_RANK + n) * PITCH + b * Lseq + c * CHUNK;

    const int NI = CHUNK / 4;           // 32 (even)
    float4 BvA, dvA[4], uvA[4];
    float4 BvB, dvB[4], uvB[4];

    BvA = *(const float4*)(pB);
    #pragma unroll
    for (int vd = 0; vd < 4; ++vd) {
        dvA[vd] = *(const float4*)(pd[vd]);
        uvA[vd] = *(const float4*)(pu[vd]);
    }

    for (int i = 0; i < NI; i += 2) {
        BvB = *(const float4*)(pB + 4 * (i + 1));
        #pragma unroll
        for (int vd = 0; vd < 4; ++vd) {
            dvB[vd] = *(const float4*)(pd[vd] + 4 * (i + 1));
            uvB[vd] = *(const float4*)(pu[vd] + 4 * (i + 1));
        }
        #pragma unroll
        for (int vd = 0; vd < 4; ++vd) {
            float a;
            a = __expf(dvA[vd].x * A[vd]); P[vd] *= a; S[vd] = a * S[vd] + (dvA[vd].x * uvA[vd].x) * BvA.x;
            a = __expf(dvA[vd].y * A[vd]); P[vd] *= a; S[vd] = a * S[vd] + (dvA[vd].y * uvA[vd].y) * BvA.y;
            a = __expf(dvA[vd].z * A[vd]); P[vd] *= a; S[vd] = a * S[vd] + (dvA[vd].z * uvA[vd].z) * BvA.z;
            a = __expf(dvA[vd].w * A[vd]); P[vd] *= a; S[vd] = a * S[vd] + (dvA[vd].w * uvA[vd].w) * BvA.w;
        }
        int i2 = (i + 2 < NI) ? (i + 2) : (NI - 1);
        BvA = *(const float4*)(pB + 4 * i2);
        #pragma unroll
        for (int vd = 0; vd < 4; ++vd) {
            dvA[vd] = *(const float4*)(pd[vd] + 4 * i2);
            uvA[vd] = *(const float4*)(pu[vd] + 4 * i2);
        }
        #pragma unroll
        for (int vd = 0; vd < 4; ++vd) {
            float a;
            a = __expf(dvB[vd].x * A[vd]); P[vd] *= a; S[vd] = a * S[vd] + (dvB[vd].x * uvB[vd].x) * BvB.x;
            a = __expf(dvB[vd].y * A[vd]); P[vd] *= a; S[vd] = a * S[vd] + (dvB[vd].y * uvB[vd].y) * BvB.y;
            a = __expf(dvB[vd].z * A[vd]); P[vd] *= a; S[vd] = a * S[vd] + (dvB[vd].z * uvB[vd].z) * BvB.z;
            a = __expf(dvB[vd].w * A[vd]); P[vd] *= a; S[vd] = a * S[vd] + (dvB[vd].w * uvB[vd].w) * BvB.w;
        }
    }
    #pragma unroll
    for (int vd = 0; vd < 4; ++vd) {
        int d = d0 + 16 * vd;
        size_t o = ((size_t)(b * NCHUNK_A + c) * D_INNER + d) * 16 + n;
        Pa[o] = P[vd];
        Sa[o] = S[vd];
    }
}

// ---------------------------------------------------------------------------
// 6b) Chunked scan, pass B: combine chunk factors, scan final chunk, emit y.
// ---------------------------------------------------------------------------
__launch_bounds__(256)
__global__ void scanB_kernel(const float* __restrict__ deltaT,
                             const float* __restrict__ uT,
                             const float* __restrict__ xdblT,
                             const float* __restrict__ A_log,
                             const float* __restrict__ Dp,
                             const float* __restrict__ Pa,
                             const float* __restrict__ Sa,
                             const float* __restrict__ z96,
                             float* __restrict__ y96) {
    int b = blockIdx.x >> 6;
    int dg = blockIdx.x & 63;
    int t = threadIdx.x;
    int d = dg * 16 + (t >> 4);
    int n = t & 15;
    float A = -__expf(A_log[d * D_STATE + n]);
    float Dd = Dp[d];
    float h = 0.f;
    for (int c = 0; c < NCHUNK_A; ++c) {
        size_t o = ((size_t)(b * NCHUNK_A + c) * D_INNER + d) * 16 + n;
        h = Pa[o] * h + Sa[o];
    }
    const int lt0 = NCHUNK_A * CHUNK;     // 1920
    size_t base = (size_t)d * PITCH + b * Lseq + lt0;
    const float* pd = deltaT + base;
    const float* pu = uT + base;
    const float* pB = xdblT + (size_t)(DT_RANK + n) * PITCH + b * Lseq + lt0;
    const float* pC = xdblT + (size_t)(DT_RANK + D_STATE + n) * PITCH + b * Lseq + lt0;

    #pragma unroll 2
    for (int i = 0; i < 8; ++i) {
        float4 dv = *(const float4*)(pd + 4 * i);
        float4 uv = *(const float4*)(pu + 4 * i);
        float4 Bv = *(const float4*)(pB + 4 * i);
        float a;
        a = __expf(dv.x * A); h = a * h + (dv.x * uv.x) * Bv.x;
        a = __expf(dv.y * A); h = a * h + (dv.y * uv.y) * Bv.y;
        a = __expf(dv.z * A); h = a * h + (dv.z * uv.z) * Bv.z;
        a = __expf(dv.w * A); h = a * h + (dv.w * uv.w) * Bv.w;
    }
    for (int i = 8; i < 32; ++i) {
        float4 dv = *(const float4*)(pd + 4 * i);
        float4 uv = *(const float4*)(pu + 4 * i);
        float4 Bv = *(const float4*)(pB + 4 * i);
        float4 Cv = *(const float4*)(pC + 4 * i);
        #pragma unroll
        for (int j = 0; j < 4; ++j) {
            float dl = (j == 0) ? dv.x : (j == 1) ? dv.y : (j == 2) ? dv.z : dv.w;
            float uu = (j == 0) ? uv.x : (j == 1) ? uv.y : (j == 2) ? uv.z : uv.w;
            float Bb = (j == 0) ? Bv.x : (j == 1) ? Bv.y : (j == 2) ? Bv.z : Bv.w;
            float Cc = (j == 0) ? Cv.x : (j == 1) ? Cv.y : (j == 2) ? Cv.z : Cv.w;
            float a = __expf(dl * A);
            h = a * h + (dl * uu) * Bb;
            float y = h * Cc;
            #pragma unroll
            for (int m = 8; m >= 1; m >>= 1) y += __shfl_xor(y, m, 16);
            if (n == 0) {
                int lz = (lt0 + 4 * i + j) - L_TAIL;   // 0..95
                size_t o = ((size_t)b * PRED_LEN + lz) * D_INNER + d;
                float z = z96[o];
                y96[o] = (y + uu * Dd) * (z / (1.f + __expf(-z)));
            }
        }
    }
}

// ---------------------------------------------------------------------------
// 7) Final head: out[b,t,c] = (y96[b,t,:] . W[c,:]) * std[b,c] + mean[b,c]
// ---------------------------------------------------------------------------
__global__ void head_kernel(const float* __restrict__ y96,
                            const float* __restrict__ W,
                            const float* __restrict__ mean,
                            const float* __restrict__ stdv,
                            float* __restrict__ out) {
    int idx = blockIdx.x;                 // 8*96*21
    int c = idx % C_OUT;
    int bt = idx / C_OUT;
    int b = bt / PRED_LEN;
    int lane = threadIdx.x;
    const float* yrow = y96 + (size_t)bt * D_INNER;
    const float* wrow = W + (size_t)c * D_INNER;
    float s = 0.f;
    for (int d = lane; d < D_INNER; d += 64) s += yrow[d] * wrow[d];
    #pragma unroll
    for (int m = 32; m >= 1; m >>= 1) s += __shfl_xor(s, m, 64);
    if (lane == 0)
        out[(size_t)bt * C_OUT + c] = s * stdv[b * C_OUT + c] + mean[b * C_OUT + c];
}

// ---------------------------------------------------------------------------
extern "C" void kernel_launch(void* const* d_in, const int* in_sizes, int n_in,
                              void* d_out, int out_size, void* d_ws, size_t ws_size,
                              hipStream_t stream) {
    const float* x_enc     = (const float*)d_in[0];
    const float* x_mark    = (const float*)d_in[1];
    const float* conv_w    = (const float*)d_in[4];
    const float* temp_w    = (const float*)d_in[5];
    const float* in_proj_w = (const float*)d_in[6];
    const float* conv1d_w  = (const float*)d_in[7];
    const float* conv1d_b  = (const float*)d_in[8];
    const float* x_proj_w  = (const float*)d_in[9];
    const float* dt_proj_w = (const float*)d_in[10];
    const float* dt_proj_b = (const float*)d_in[11];
    const float* A_log     = (const float*)d_in[12];
    const float* Dp        = (const float*)d_in[13];
    const float* out_proj_w= (const float*)d_in[14];
    const float* head_w    = (const float*)d_in[15];
    float* out = (float*)d_out;
    float* ws = (float*)d_ws;

    // workspace layout (floats) — NO aliasing. ~61.2M floats = 244.7 MB.
    size_t off = 0;
    float* mean     = ws + off; off += 256;
    float* stdv     = ws + off; off += 256;
    float* W        = ws + off; off += (size_t)C_OUT * D_INNER;            // 21504
    float* WembT    = ws + off; off += (size_t)K_EMB * D_MODEL;            // 40960
    float* Wcomb    = ws + off; off += (size_t)2 * D_INNER * K_EMB;        // 163840
    float* PEpT     = ws + off; off += (size_t)D_INNER * Lseq;             // 2.10M
    float* PEpZ     = ws + off; off += (size_t)PRED_LEN * D_INNER;         // 98304
    float* xin      = ws + off; off += (size_t)K_EMB * MTOT;               // 1.31M
    float* xs_rawT  = ws + off; off += (size_t)D_INNER * MTOT;             // 16.8M
    float* z96      = ws + off; off += (size_t)Bsz * PRED_LEN * D_INNER;   // 0.79M
    float* xs_convT = ws + off; off += (size_t)D_INNER * PITCH;            // 16.8M
    float* xdblT    = ws + off; off += (size_t)64 * PITCH;                 // 1.05M
    float* deltaT   = ws + off; off += (size_t)D_INNER * PITCH;            // 16.8M
    float* Pa       = ws + off; off += (size_t)Bsz * NCHUNK_A * D_INNER * D_STATE; // 1.97M
    float* Sa       = ws + off; off += (size_t)Bsz * NCHUNK_A * D_INNER * D_STATE; // 1.97M
    float* y96      = ws + off; off += (size_t)Bsz * PRED_LEN * D_INNER;   // 0.79M
    float* xdbl_rm  = ws + off; off += (size_t)MTOT * DT_RANK;             // 0.52M

    // 1) instance-norm stats (one pass)
    stats_kernel<<<Bsz * ENC_IN, 256, 0, stream>>>(x_enc, mean, stdv);
    // 2) fused output weight
    fuse_w_kernel<<<(C_OUT * D_INNER + 255) / 256, 256, 0, stream>>>(head_w, out_proj_w, W);
    // 3) precomputations
    prep_wT_kernel<<<(K_EMB * D_MODEL) / 256, 256, 0, stream>>>(conv_w, temp_w, WembT);
    prep_x_kernel<<<(MTOT * K_EMB) / 256, 256, 0, stream>>>(x_enc, x_mark, mean, stdv, xin);
    wcomb_kernel<<<(2 * D_INNER * K_EMB) / 256, 256, 0, stream>>>(in_proj_w, WembT, Wcomb);
    pepz_kernel<<<dim3(PRED_LEN, 4), 256, 0, stream>>>(in_proj_w, PEpZ);
    // PEpT[j][l] = in_proj_xs @ pe^T  (MFMA 64-tile, analytic B; 512 blocks)
    mfma_gemm64<1, 0><<<dim3(Lseq / 64, D_INNER / 64), 256, 0, stream>>>(
        in_proj_w, nullptr, PEpT, nullptr, D_INNER, Lseq, D_MODEL, D_MODEL, 0, Lseq);
    // 4a) xs_rawT[j][bl] = Wcomb_xs @ xin^T + PEpT[j][l]  (MFMA, row-major B)
    mfma_gemm128<2, 2><<<dim3(MTOT / 64, D_INNER / 128), 256, 0, stream>>>(
        Wcomb, xin, xs_rawT, PEpT, D_INNER, MTOT, K_EMB, K_EMB, K_EMB, MTOT);
    // 4b) z96[bt][d] = xin[tail-remap] @ Wcomb_z^T + PEpZ[bt%96][d]  (fp32)
    gemm<3, 0, 3><<<dim3(D_INNER / 64, (Bsz * PRED_LEN) / 64), 256, 0, stream>>>(
        xin, Wcomb + (size_t)D_INNER * K_EMB, z96, PEpZ,
        Bsz * PRED_LEN, D_INNER, K_EMB, K_EMB, K_EMB);
    // 5) depthwise causal conv + SiLU (writes PITCH-padded xs_convT)
    dwconv_kernel<<<D_INNER * 16, 256, 0, stream>>>(xs_rawT, conv1d_w, conv1d_b, xs_convT);
    // 6) xdblT[p][bl] = x_proj_w @ xs_convT  (split-K x4, atomic accumulate)
    zero_kernel<<<(64 * PITCH) / 4 / 256, 256, 0, stream>>>((float4*)xdblT);
    mfma_gemm_splitk<<<dim3(MTOT / 64, 1, 4), 256, 0, stream>>>(
        x_proj_w, xs_convT, xdblT, 64, MTOT, D_INNER, D_INNER, PITCH, PITCH, 256);
    // 6b) transpose rank rows -> xdbl_rm[bl][32]
    xdbl_tr_kernel<<<MTOT / 64, 256, 0, stream>>>(xdblT, xdbl_rm);
    // 7) deltaT[d][bl] = softplus(dt_proj_w @ xdbl_rm^T + dt_b[d])  (MFMA)
    mfma_gemm128<2, 1><<<dim3(MTOT / 64, D_INNER / 128), 256, 0, stream>>>(
        dt_proj_w, xdbl_rm, deltaT, dt_proj_b, D_INNER, MTOT, DT_RANK, DT_RANK, DT_RANK, PITCH);
    // 8) chunked selective scan (R13 4-chain pass A)
    scanA_kernel<<<dim3(Bsz * 16, NCHUNK_A), 256, 0, stream>>>(
        deltaT, xs_convT, xdblT, A_log, Pa, Sa);
    scanB_kernel<<<Bsz * 64, 256, 0, stream>>>(
        deltaT, xs_convT, xdblT, A_log, Dp, Pa, Sa, z96, y96);
    // 9) head + de-normalize
    head_kernel<<<Bsz * PRED_LEN * C_OUT, 64, 0, stream>>>(y96, W, mean, stdv, out);
}